// Round 5
// baseline (44691.199 us; speedup 1.0000x reference)
//
#include <hip/hip_runtime.h>

#define B_ 32
#define S_ 64
#define V_ 96
#define E_ 256
#define H_ 512
#define L_ 3
#define DIN_ 1024
#define G4_ 2048
#define BH_ (B_*H_)
#define NB_ 256            // blocks in persistent kernels (<= 256 CUs -> co-resident)
#define NW_ (NB_*4)        // waves in persistent kernels

__device__ __forceinline__ float sigm(float x){ return 1.f/(1.f+__expf(-x)); }
__device__ __forceinline__ float wred(float a){
  #pragma unroll
  for(int off=32; off; off>>=1) a += __shfl_down(a, off);
  return a;
}

// Device-scope grid barrier. bar[0]=count, bar[1]=generation; both zeroed
// once per kernel_launch. Safe under graph replay (count returns to 0 after
// every completed barrier; generation just keeps incrementing).
__device__ __forceinline__ void gsync(int* bar){
  __syncthreads();
  if(threadIdx.x == 0){
    __threadfence();   // make this block's writes visible device-wide
    int gen = __hip_atomic_load(bar+1, __ATOMIC_RELAXED, __HIP_MEMORY_SCOPE_AGENT);
    int v = __hip_atomic_fetch_add(bar, 1, __ATOMIC_ACQ_REL, __HIP_MEMORY_SCOPE_AGENT);
    if(v == NB_-1){
      __hip_atomic_store(bar, 0, __ATOMIC_RELAXED, __HIP_MEMORY_SCOPE_AGENT);
      __hip_atomic_fetch_add(bar+1, 1, __ATOMIC_RELEASE, __HIP_MEMORY_SCOPE_AGENT);
    } else {
      while(__hip_atomic_load(bar+1, __ATOMIC_ACQUIRE, __HIP_MEMORY_SCOPE_AGENT) == gen){
        __builtin_amdgcn_s_sleep(2);
      }
    }
    __threadfence();
  }
  __syncthreads();
}

// ---------------------------------------------------------------------------
__global__ void k_zero(float* __restrict__ p, int n){
  int i = blockIdx.x*256 + threadIdx.x;
  if(i < n) p[i] = 0.f;
}

// ---------------------------------------------------------------------------
// X0[(s*B+b)*DIN + d] = emb[src[b,s], d] (d<E), else 0.
__global__ void k_embed(const int* __restrict__ src, const float* __restrict__ emb,
                        float* __restrict__ X0){
  int idx = blockIdx.x*256 + threadIdx.x;   // exactly S*B*DIN threads
  int d  = idx & (DIN_-1);
  int sb = idx >> 10;
  int b  = sb & (B_-1);
  int s  = sb >> 5;
  float v = 0.f;
  if(d < E_){
    int tok = src[b*S_ + s];
    v = emb[(size_t)tok*E_ + d];
  }
  X0[idx] = v;
}

// ---------------------------------------------------------------------------
// Tiled fp32 GEMM: C[m,n] = sum_k A[m*lda+k]*W[woff+n*ldw+k] + b1[n] + b2[n]
// Tile 128(m) x 64(n), 256 threads, 8x4 per thread, K multiple of 16.
__global__ __launch_bounds__(256) void k_gemm(
  const float* __restrict__ A, int lda,
  const float* __restrict__ W, int ldw, size_t woff,
  const float* __restrict__ b1, size_t o1,
  const float* __restrict__ b2, size_t o2,
  float* __restrict__ C, int ldc, int K)
{
  __shared__ float As[16][128];
  __shared__ float Bs[16][64];
  const int tid = threadIdx.x;
  const int m0 = blockIdx.y * 128;
  const int n0 = blockIdx.x * 64;
  const int tx = tid & 15, ty = tid >> 4;
  const int amm = tid & 127, akk = (tid >> 7) * 8;
  const int bnn = tid >> 2,  bkk = (tid & 3) * 4;
  float acc[8][4] = {{0.f}};
  for(int k0 = 0; k0 < K; k0 += 16){
    const float4* ap = (const float4*)(A + (size_t)(m0+amm)*lda + (k0 + akk));
    float4 a0 = ap[0];
    float4 a1 = ap[1];
    float4 wv = *(const float4*)(W + woff + (size_t)(n0+bnn)*ldw + (k0 + bkk));
    As[akk+0][amm]=a0.x; As[akk+1][amm]=a0.y; As[akk+2][amm]=a0.z; As[akk+3][amm]=a0.w;
    As[akk+4][amm]=a1.x; As[akk+5][amm]=a1.y; As[akk+6][amm]=a1.z; As[akk+7][amm]=a1.w;
    Bs[bkk+0][bnn]=wv.x; Bs[bkk+1][bnn]=wv.y;
    Bs[bkk+2][bnn]=wv.z; Bs[bkk+3][bnn]=wv.w;
    __syncthreads();
    #pragma unroll
    for(int kk=0;kk<16;kk++){
      const float4 av0 = *(const float4*)&As[kk][ty*8];
      const float4 av1 = *(const float4*)&As[kk][ty*8+4];
      const float4 bv  = *(const float4*)&Bs[kk][tx*4];
      float am[8] = {av0.x,av0.y,av0.z,av0.w,av1.x,av1.y,av1.z,av1.w};
      float bn[4] = {bv.x,bv.y,bv.z,bv.w};
      #pragma unroll
      for(int i=0;i<8;i++){
        #pragma unroll
        for(int j=0;j<4;j++) acc[i][j] = fmaf(am[i], bn[j], acc[i][j]);
      }
    }
    __syncthreads();
  }
  float bias[4];
  #pragma unroll
  for(int j=0;j<4;j++){
    float bb = 0.f;
    if(b1) bb += b1[o1 + n0 + tx*4 + j];
    if(b2) bb += b2[o2 + n0 + tx*4 + j];
    bias[j] = bb;
  }
  #pragma unroll
  for(int i=0;i<8;i++){
    float* cp = C + (size_t)(m0 + ty*8 + i)*ldc + (n0 + tx*4);
    #pragma unroll
    for(int j=0;j<4;j++) cp[j] = acc[i][j] + bias[j];
  }
}

// ---------------------------------------------------------------------------
// Persistent encoder layer: runs all 64 recurrent steps in one launch.
// useG=1: gates pre-GEMMed into G [(t*B+b)*4096 + d*2048 + gate*512 + j]
// useG=0: computes x@Wih inline from Xin (plan B, no G buffer).
// st: [2 parity][4][BH] = hf,cf,hb,cb per parity. Final states -> parity 0.
// Also writes Xn (next-layer input / enc_out) and decinit dh,dc for layer l.
__global__ __launch_bounds__(256) void k_enc_layer(
  const float* __restrict__ G, const float* __restrict__ Xin,
  const float* __restrict__ Wih, const float* __restrict__ Whh,
  const float* __restrict__ bih, const float* __restrict__ bhh,
  float* __restrict__ st, float* __restrict__ Xn,
  float* __restrict__ dh, float* __restrict__ dc,
  int Kx, int useG, int* bar)
{
  const int wid = blockIdx.x*4 + (threadIdx.x>>6);
  const int lane = threadIdx.x & 63;
  // zero parity-0 states
  for(int i = blockIdx.x*256 + threadIdx.x; i < 4*BH_; i += NB_*256) st[i] = 0.f;
  gsync(bar);
  for(int p=0;p<S_;p++){
    const int cpar = (p&1)*4, npar = cpar^4;
    for(int task = wid; task < 32768; task += NW_){
      const int j = task & 511;
      const int b = (task>>9) & 31;
      const int d = task >> 14;
      const int t = d ? (S_-1-p) : p;
      const float* hrow = st + (size_t)(cpar + 2*d)*BH_ + b*H_;
      const size_t wb = ((size_t)d*G4_ + j) * H_;
      float a0=0.f,a1=0.f,a2=0.f,a3=0.f;
      if(!useG){
        const float* xr = Xin + (size_t)(t*B_ + b)*DIN_;
        const size_t wi = ((size_t)d*G4_ + j) * DIN_;
        for(int k=lane; k<Kx; k+=64){
          float xv = xr[k];
          a0 = fmaf(xv, Wih[wi + k], a0);
          a1 = fmaf(xv, Wih[wi + (size_t)H_*DIN_ + k], a1);
          a2 = fmaf(xv, Wih[wi + (size_t)2*H_*DIN_ + k], a2);
          a3 = fmaf(xv, Wih[wi + (size_t)3*H_*DIN_ + k], a3);
        }
      }
      #pragma unroll
      for(int i=0;i<8;i++){
        int k = lane + i*64;
        float hv = hrow[k];
        a0 = fmaf(hv, Whh[wb + k], a0);
        a1 = fmaf(hv, Whh[wb + (size_t)H_*H_ + k], a1);
        a2 = fmaf(hv, Whh[wb + (size_t)2*H_*H_ + k], a2);
        a3 = fmaf(hv, Whh[wb + (size_t)3*H_*H_ + k], a3);
      }
      a0 = wred(a0); a1 = wred(a1); a2 = wred(a2); a3 = wred(a3);
      if(lane == 0){
        float gi, gf, gg, go;
        if(useG){
          const float* Gr = G + (size_t)(t*B_ + b)*4096 + d*G4_ + j;
          gi = Gr[0] + a0; gf = Gr[H_] + a1; gg = Gr[2*H_] + a2; go = Gr[3*H_] + a3;
        } else {
          size_t bb = (size_t)d*G4_ + j;
          gi = a0 + bih[bb]       + bhh[bb];
          gf = a1 + bih[bb+H_]    + bhh[bb+H_];
          gg = a2 + bih[bb+2*H_]  + bhh[bb+2*H_];
          go = a3 + bih[bb+3*H_]  + bhh[bb+3*H_];
        }
        float cin = st[(size_t)(cpar + 2*d + 1)*BH_ + b*H_ + j];
        float c2 = sigm(gf)*cin + sigm(gi)*tanhf(gg);
        float h2 = sigm(go)*tanhf(c2);
        st[(size_t)(npar + 2*d)*BH_ + b*H_ + j]     = h2;
        st[(size_t)(npar + 2*d + 1)*BH_ + b*H_ + j] = c2;
        Xn[(size_t)(t*B_ + b)*DIN_ + d*H_ + j] = h2;
      }
    }
    gsync(bar);
  }
  // final states are in parity 0 (p=63 writes npar=0). decinit: dh=hf+hb, dc=cf+cb
  for(int i = blockIdx.x*256 + threadIdx.x; i < BH_; i += NB_*256){
    dh[i] = st[i] + st[2*BH_ + i];
    dc[i] = st[BH_ + i] + st[3*BH_ + i];
  }
}

// ---------------------------------------------------------------------------
// Persistent decoder: all 63 steps in one launch.
// dst: dh[2][3][BH] then dc[2][3][BH]. Phases per step with grid barriers.
__global__ __launch_bounds__(256) void k_dec_all(
  const int* __restrict__ trg, const float* __restrict__ emb,
  const float* __restrict__ Epre, const float* __restrict__ X3,
  const float* __restrict__ dWih, const float* __restrict__ dWhh,
  const float* __restrict__ dbih, const float* __restrict__ dbhh,
  const float* __restrict__ aW, const float* __restrict__ av,
  const float* __restrict__ pW, const float* __restrict__ pb,
  const float* __restrict__ fW, const float* __restrict__ fb,
  float* __restrict__ dst, float* __restrict__ zbuf,
  float* __restrict__ scbuf, float* __restrict__ ctx, float* __restrict__ xp,
  float* __restrict__ out, int* bar)
{
  const int wid = blockIdx.x*4 + (threadIdx.x>>6);
  const int lane = threadIdx.x & 63;
  float* dhp[2] = { dst, dst + 3*BH_ };
  float* dcp[2] = { dst + 6*BH_, dst + 9*BH_ };
  // out[b,0,:] = 0
  for(int i = blockIdx.x*256 + threadIdx.x; i < B_*V_; i += NB_*256){
    int b = i / V_, v = i - b*V_;
    out[(size_t)b*S_*V_ + v] = 0.f;
  }
  for(int t=0;t<S_-1;t++){
    const int c = t&1, n = c^1;
    const float* htop = dhp[c] + 2*BH_;
    // ---- phase 1: z = htop @ W1.T   (+ fc of previous step, independent)
    {
      int ntask = 16384 + (t>0 ? B_*V_ : 0);
      for(int task = wid; task < ntask; task += NW_){
        if(task < 16384){
          int j = task & 511, b = task >> 9;
          const float* wr = aW + (size_t)j*(3*H_);
          const float* hr = htop + b*H_;
          float a = 0.f;
          #pragma unroll
          for(int i=0;i<8;i++){ int k = lane + i*64; a = fmaf(hr[k], wr[k], a); }
          a = wred(a);
          if(lane==0) zbuf[b*H_ + j] = a;
        } else {
          int q = task - 16384; int v = q % V_, b = q / V_;
          const float* hr = htop + b*H_;
          float a = 0.f;
          #pragma unroll
          for(int i=0;i<8;i++){ int k = lane + i*64; a = fmaf(hr[k], fW[(size_t)v*H_ + k], a); }
          a = wred(a);
          if(lane==0) out[(size_t)b*S_*V_ + (size_t)t*V_ + v] = a + fb[v];
        }
      }
    }
    gsync(bar);
    // ---- phase 2: scores[b][s] = v . tanh(Epre[s,b] + z[b])
    for(int task = wid; task < 2048; task += NW_){
      int s = task & 63, b = task >> 6;
      const float* ep = Epre + (size_t)(s*B_ + b)*H_;
      const float* zz = zbuf + b*H_;
      float a = 0.f;
      #pragma unroll
      for(int i=0;i<8;i++){
        int k = lane + i*64;
        a = fmaf(av[k], tanhf(ep[k] + zz[k]), a);
      }
      a = wred(a);
      if(lane==0) scbuf[b*64 + s] = a;
    }
    gsync(bar);
    // ---- phase 3: softmax (redundant per wave) + ctx
    for(int task = wid; task < 512; task += NW_){
      int ch = task & 15, b = task >> 4;
      float sv = scbuf[b*64 + lane];
      float m = sv;
      #pragma unroll
      for(int off=32; off; off>>=1) m = fmaxf(m, __shfl_down(m, off));
      m = __shfl(m, 0);
      float e = __expf(sv - m);
      float sum = wred(e);
      sum = __shfl(sum, 0);
      float pr = e / sum;
      int dim = ch*64 + lane;
      float a = 0.f;
      for(int s=0;s<64;s++){
        float ps = __shfl(pr, s);
        a = fmaf(ps, X3[(size_t)(s*B_ + b)*DIN_ + dim], a);
      }
      ctx[b*DIN_ + dim] = a;
    }
    gsync(bar);
    // ---- phase 4: xp = [emb[trg[:,t]], ctx] @ proj_W.T + proj_b
    for(int task = wid; task < 32768; task += NW_){
      int j = task & 1023, b = task >> 10;
      int tok = trg[b*S_ + t];
      const float* wr = pW + (size_t)j*(E_ + 2*H_);
      float a = 0.f;
      #pragma unroll
      for(int i=0;i<4;i++){
        int k = lane + i*64;
        a = fmaf(emb[(size_t)tok*E_ + k], wr[k], a);
      }
      const float* cr = ctx + (size_t)b*DIN_;
      #pragma unroll
      for(int i=0;i<16;i++){
        int k = lane + i*64;
        a = fmaf(cr[k], wr[E_ + k], a);
      }
      a = wred(a);
      if(lane==0) xp[(size_t)b*DIN_ + j] = a + pb[j];
    }
    gsync(bar);
    // ---- phases 5-7: LSTM cells
    for(int l=0;l<L_;l++){
      const float* xbase = (l==0) ? xp : (dhp[n] + (size_t)(l-1)*BH_);
      const int Kx = (l==0) ? DIN_ : H_;
      const size_t oWi = (size_t)l*G4_*DIN_;
      const size_t oWh = (size_t)l*G4_*H_;
      const size_t ob  = (size_t)l*G4_;
      for(int task = wid; task < 16384; task += NW_){
        int j = task & 511, b = task >> 9;
        const float* xr = xbase + (size_t)b*Kx;
        const size_t wi = oWi + (size_t)j*DIN_;
        float a0=0.f,a1=0.f,a2=0.f,a3=0.f;
        for(int k=lane; k<Kx; k+=64){
          float xv = xr[k];
          a0 = fmaf(xv, dWih[wi + k], a0);
          a1 = fmaf(xv, dWih[wi + (size_t)H_*DIN_ + k], a1);
          a2 = fmaf(xv, dWih[wi + (size_t)2*H_*DIN_ + k], a2);
          a3 = fmaf(xv, dWih[wi + (size_t)3*H_*DIN_ + k], a3);
        }
        const size_t wh = oWh + (size_t)j*H_;
        const float* hrow = dhp[c] + (size_t)l*BH_ + b*H_;
        #pragma unroll
        for(int i=0;i<8;i++){
          int k = lane + i*64;
          float hv = hrow[k];
          a0 = fmaf(hv, dWhh[wh + k], a0);
          a1 = fmaf(hv, dWhh[wh + (size_t)H_*H_ + k], a1);
          a2 = fmaf(hv, dWhh[wh + (size_t)2*H_*H_ + k], a2);
          a3 = fmaf(hv, dWhh[wh + (size_t)3*H_*H_ + k], a3);
        }
        a0 = wred(a0); a1 = wred(a1); a2 = wred(a2); a3 = wred(a3);
        if(lane==0){
          float gi = a0 + dbih[ob+j]       + dbhh[ob+j];
          float gf = a1 + dbih[ob+j+H_]    + dbhh[ob+j+H_];
          float gg = a2 + dbih[ob+j+2*H_]  + dbhh[ob+j+2*H_];
          float go = a3 + dbih[ob+j+3*H_]  + dbhh[ob+j+3*H_];
          float cin = dcp[c][(size_t)l*BH_ + b*H_ + j];
          float c2 = sigm(gf)*cin + sigm(gi)*tanhf(gg);
          float h2 = sigm(go)*tanhf(c2);
          dhp[n][(size_t)l*BH_ + b*H_ + j] = h2;
          dcp[n][(size_t)l*BH_ + b*H_ + j] = c2;
        }
      }
      gsync(bar);
    }
  }
  // final fc: output slot 63 from state parity 1 (after t=62, n=1)
  const float* htop = dhp[1] + 2*BH_;
  for(int task = wid; task < B_*V_; task += NW_){
    int v = task % V_, b = task / V_;
    const float* hr = htop + b*H_;
    float a = 0.f;
    #pragma unroll
    for(int i=0;i<8;i++){ int k = lane + i*64; a = fmaf(hr[k], fW[(size_t)v*H_ + k], a); }
    a = wred(a);
    if(lane==0) out[(size_t)b*S_*V_ + (size_t)63*V_ + v] = a + fb[v];
  }
}

// ---------------------------------------------------------------------------
extern "C" void kernel_launch(void* const* d_in, const int* in_sizes, int n_in,
                              void* d_out, int out_size, void* d_ws, size_t ws_size,
                              hipStream_t stream){
  const int* src  = (const int*)d_in[0];
  const int* trg  = (const int*)d_in[1];
  const float* emb = (const float*)d_in[2];
  const float* eWih= (const float*)d_in[3];
  const float* eWhh= (const float*)d_in[4];
  const float* ebih= (const float*)d_in[5];
  const float* ebhh= (const float*)d_in[6];
  const float* dWih= (const float*)d_in[7];
  const float* dWhh= (const float*)d_in[8];
  const float* dbih= (const float*)d_in[9];
  const float* dbhh= (const float*)d_in[10];
  const float* aW  = (const float*)d_in[11];
  const float* ab  = (const float*)d_in[12];
  const float* av  = (const float*)d_in[13];
  const float* pW  = (const float*)d_in[14];
  const float* pb  = (const float*)d_in[15];
  const float* fW  = (const float*)d_in[16];
  const float* fb  = (const float*)d_in[17];
  float* out = (float*)d_out;

  char* base = (char*)d_ws;
  size_t off = 0;
  auto take = [&](size_t bytes)->char*{
    char* p = base + off; off = (off + bytes + 255) & ~(size_t)255; return p;
  };

  const size_t szX  = (size_t)2048*1024*4;   // 8 MB
  const size_t szG  = (size_t)2048*4096*4;   // 32 MB
  const size_t szE  = (size_t)2048*512*4;    // 4 MB
  // fixed-small regions after optional G:
  const size_t szSmall = (size_t)8*BH_*4     // enc st
                       + (size_t)12*BH_*4    // dec state
                       + (16384 + 2048 + 32768 + 32768)*4  // z, sc, ctx, xp
                       + 4096;               // barrier + pad
  int planA = (ws_size >= 2*szX + szG + szE + szSmall + 8192);

  float* XA  = (float*)take(szX);
  float* XB  = (float*)take(szX);
  float* G   = planA ? (float*)take(szG) : nullptr;
  float* Epre= (float*)take(szE);
  float* est = (float*)take((size_t)8*BH_*4);
  float* dst = (float*)take((size_t)12*BH_*4);
  float* zbuf= (float*)take(16384*4);
  float* scb = (float*)take(2048*4);
  float* ctx = (float*)take(32768*4);
  float* xp  = (float*)take(32768*4);
  int*   bar = (int*)take(256);

  k_zero<<<1, 256, 0, stream>>>((float*)bar, 2);
  k_embed<<<8192, 256, 0, stream>>>(src, emb, XA);

  float* Xin = XA; float* Xout = XB;
  for(int l=0;l<L_;l++){
    int K = (l==0) ? E_ : DIN_;   // layer-0 pad cols are zero -> skip
    if(planA){
      k_gemm<<<dim3(64,16), 256, 0, stream>>>(Xin, DIN_,
          eWih + (size_t)l*2*G4_*DIN_, DIN_, 0,
          ebih, (size_t)l*2*G4_, ebhh, (size_t)l*2*G4_, G, 4096, K);
    }
    k_enc_layer<<<NB_, 256, 0, stream>>>(G, Xin,
        eWih + (size_t)l*2*G4_*DIN_, eWhh + (size_t)l*2*G4_*H_,
        ebih + (size_t)l*2*G4_, ebhh + (size_t)l*2*G4_,
        est, Xout, dst + (size_t)l*BH_, dst + (size_t)(6+l)*BH_,
        K, planA ? 1 : 0, bar);
    float* tmp = Xin; Xin = Xout; Xout = tmp;
  }
  // Epre = enc_out @ attn_W[:, H:].T + attn_b   (step-invariant)
  k_gemm<<<dim3(8,16), 256, 0, stream>>>(Xin, DIN_, aW, 3*H_, (size_t)H_,
                                         ab, 0, nullptr, 0, Epre, H_, DIN_);
  k_dec_all<<<NB_, 256, 0, stream>>>(trg, emb, Epre, Xin,
      dWih, dWhh, dbih, dbhh, aW, av, pW, pb, fW, fb,
      dst, zbuf, scb, ctx, xp, out, bar);
}